// Round 12
// baseline (686.413 us; speedup 1.0000x reference)
//
#include <hip/hip_runtime.h>
#include <cstdint>

#define NTOK 8192
#define DIM  1024
#define HID  2048
#define MATE (2048*1024)

typedef __attribute__((ext_vector_type(8))) short short8;
typedef __attribute__((ext_vector_type(4))) float f32x4;

typedef unsigned int __attribute__((address_space(1)))* gptr_t;
typedef unsigned int __attribute__((address_space(3)))* lptr_t;

__device__ __forceinline__ unsigned short f2bf(float f) {
  unsigned u = __builtin_bit_cast(unsigned, f);
  u += 0x7fffu + ((u >> 16) & 1u);
  return (unsigned short)(u >> 16);
}
__device__ __forceinline__ float bf2f(unsigned short h) {
  unsigned u = ((unsigned)h) << 16;
  return __builtin_bit_cast(float, u);
}

__device__ __forceinline__ void gl_lds16(const void* g, void* l) {
  __builtin_amdgcn_global_load_lds((gptr_t)g, (lptr_t)l, 16, 0, 0);
}

#define BAR()        asm volatile("s_barrier" ::: "memory")
#define WAIT_VM(N)   asm volatile("s_waitcnt vmcnt(" #N ")" ::: "memory")
#define WAIT_VM0()   asm volatile("s_waitcnt vmcnt(0)" ::: "memory")

// ---------------- gating + x->bf16 cast (fused) ----------------
__global__ __launch_bounds__(256) void k_gate(const float* __restrict__ x,
    const float* __restrict__ gw, int* __restrict__ topi, float* __restrict__ topw,
    int* __restrict__ counts, unsigned short* __restrict__ xb)
{
  int lane = threadIdx.x & 63;
  int t = blockIdx.x * 4 + (threadIdx.x >> 6);
  const float* xr = x + (size_t)t * DIM;
  unsigned short* xbr = xb + (size_t)t * DIM;
  float a0=0,a1=0,a2=0,a3=0,a4=0,a5=0,a6=0,a7=0;
  for (int i = 0; i < 16; ++i) {
    int idx = lane + (i << 6);
    float xv = xr[idx];
    xbr[idx] = f2bf(xv);
    float4 g0 = *reinterpret_cast<const float4*>(gw + idx*8);
    float4 g1 = *reinterpret_cast<const float4*>(gw + idx*8 + 4);
    a0 += xv*g0.x; a1 += xv*g0.y; a2 += xv*g0.z; a3 += xv*g0.w;
    a4 += xv*g1.x; a5 += xv*g1.y; a6 += xv*g1.z; a7 += xv*g1.w;
  }
  float acc[8] = {a0,a1,a2,a3,a4,a5,a6,a7};
  #pragma unroll
  for (int e = 0; e < 8; ++e)
    for (int off = 32; off >= 1; off >>= 1)
      acc[e] += __shfl_xor(acc[e], off, 64);
  if (lane == 0) {
    int i0 = 0; float v0 = acc[0];
    #pragma unroll
    for (int e = 1; e < 8; ++e) if (acc[e] > v0) { v0 = acc[e]; i0 = e; }
    int i1 = -1; float v1 = -3.4e38f;
    #pragma unroll
    for (int e = 0; e < 8; ++e) if (e != i0 && acc[e] > v1) { v1 = acc[e]; i1 = e; }
    float p0 = 1.f / (1.f + __expf(v1 - v0));
    topi[2*t] = i0; topi[2*t+1] = i1;
    topw[2*t] = p0; topw[2*t+1] = 1.f - p0;
    atomicAdd(&counts[i0], 1); atomicAdd(&counts[i1], 1);
  }
}

__global__ void k_scan(const int* __restrict__ counts, int* __restrict__ offs,
                       int* __restrict__ fill)
{
  if (threadIdx.x == 0) {
    int s = 0;
    for (int e = 0; e < 8; ++e) { offs[e] = s; fill[e] = s; s += counts[e]; }
    offs[8] = s;
  }
}

__global__ __launch_bounds__(256) void k_scatter(const int* __restrict__ topi,
    int* __restrict__ fill, int* __restrict__ entry, int* __restrict__ slot)
{
  int t = blockIdx.x * 256 + threadIdx.x;
  #pragma unroll
  for (int k = 0; k < 2; ++k) {
    int e = topi[2*t + k];
    int pos = atomicAdd(&fill[e], 1);
    entry[pos] = t;
    slot[2*t + k] = pos;
  }
}

// ------------- weight transpose+cast: src f32 [R][C] -> dst bf16 [C][R] -------------
__global__ __launch_bounds__(256) void k_tr(const float* __restrict__ ew1,
    const float* __restrict__ ew2, const float* __restrict__ ew3,
    const float* __restrict__ sw1, const float* __restrict__ sw2,
    const float* __restrict__ sw3, unsigned short* __restrict__ wt)
{
  int id = blockIdx.x;          // 0..3455
  int z = id >> 7, t = id & 127;
  const float* src; int R, C;
  if (z < 8)        { src = ew1 + (size_t)z * MATE;      R = 1024; C = 2048; }
  else if (z < 16)  { src = ew2 + (size_t)(z-8) * MATE;  R = 1024; C = 2048; }
  else if (z < 24)  { src = ew3 + (size_t)(z-16) * MATE; R = 2048; C = 1024; }
  else if (z == 24) { src = sw1; R = 1024; C = 2048; }
  else if (z == 25) { src = sw2; R = 1024; C = 2048; }
  else              { src = sw3; R = 2048; C = 1024; }
  unsigned short* dst = wt + (size_t)z * MATE;
  int tr, tc;
  if (C == 2048) { tr = t >> 3; tc = t & 7; }
  else           { tr = t >> 2; tc = t & 3; }
  int rb = tr * 64, cb = tc * 256;
  __shared__ float tile[64][257];
  int tid = threadIdx.x;
  {
    int r0 = tid >> 6, c4 = (tid & 63) * 4;
    #pragma unroll
    for (int i = 0; i < 16; ++i) {
      int r = r0 + i*4;
      float4 v = *reinterpret_cast<const float4*>(src + (size_t)(rb + r) * C + cb + c4);
      tile[r][c4 + 0] = v.x; tile[r][c4 + 1] = v.y;
      tile[r][c4 + 2] = v.z; tile[r][c4 + 3] = v.w;
    }
  }
  __syncthreads();
  {
    int r0 = (tid & 7) * 8, ccb = tid >> 3;
    #pragma unroll
    for (int p = 0; p < 8; ++p) {
      int cc = ccb + p*32;
      short8 o;
      #pragma unroll
      for (int i = 0; i < 8; ++i) o[i] = (short)f2bf(tile[r0 + i][cc]);
      *reinterpret_cast<short8*>(dst + (size_t)(cb + cc) * R + rb + r0) = o;
    }
  }
}

// ============ up-proj (dual-B) + SwiGLU, BM=256/BN=128x2/BK=32 ============
// Depth-2 counted-vmcnt pipeline, 3 LDS buffers (96 KB), one barrier per K-tile.
// 512 threads = 8 waves (4M x 2N). Per buf 32KB: A[256][32]@0, B1[128][32]@16384, B2@24576.
// Staging/swizzle geometry identical to proven R8 kernel.
__global__ __launch_bounds__(512, 2) void k_up(const unsigned short* __restrict__ xb,
    const unsigned short* __restrict__ wt, const int* __restrict__ offs,
    const int* __restrict__ entry, unsigned short* __restrict__ act)
{
  __shared__ __align__(16) unsigned short L[3][16384];   // 96 KB
  int tid = threadIdx.x, lane = tid & 63, w = tid >> 6;
  int nb = blockIdx.x, yb = blockIdx.y;
  int mbase, mend, arow0; const unsigned short *w1, *w2; bool is_sh;
  if (yb < 256) {
    int seg = yb >> 5, mb = yb & 31;
    int s0 = offs[seg], s1 = offs[seg+1];
    mbase = s0 + mb*256; if (mbase >= s1) return;
    mend = s1; arow0 = mbase;
    w1 = wt + (size_t)seg * MATE; w2 = wt + (size_t)(8+seg) * MATE; is_sh = false;
  } else {
    int mb = yb - 256; mbase = mb*256; mend = NTOK; arow0 = 16384 + mbase;
    w1 = wt + (size_t)24 * MATE; w2 = wt + (size_t)25 * MATE; is_sh = true;
  }
  int srow = w*16 + (lane >> 2);
  int swz = (((lane & 3) ^ ((lane >> 3) & 3))) * 8;
  const unsigned short* pA[2];
  #pragma unroll
  for (int j = 0; j < 2; ++j) {
    int mi = mbase + j*128 + srow;
    int tok = is_sh ? mi : ((mi < mend) ? entry[mi] : 0);
    pA[j] = xb + (size_t)tok * DIM + swz;
  }
  int n0 = nb * 128;
  const unsigned short* pB1 = w1 + (size_t)(n0 + srow) * DIM + swz;
  const unsigned short* pB2 = w2 + (size_t)(n0 + srow) * DIM + swz;
  unsigned tq = (unsigned)tid * 16u;
  int r16 = lane & 15, kg = lane >> 4, wm = w >> 1, wn = w & 1;
  int rk = (r16 >> 1) & 3;
  int rdA = (wm*64 + r16)*64 + ((kg ^ rk) << 4);
  int rdB = (wn*64 + r16)*64 + ((kg ^ rk) << 4);
  const f32x4 fz = {0.f,0.f,0.f,0.f};
  f32x4 acc1[4][4], acc2[4][4];
  #pragma unroll
  for (int m = 0; m < 4; ++m)
    #pragma unroll
    for (int n = 0; n < 4; ++n) { acc1[m][n] = fz; acc2[m][n] = fz; }

  auto STAGE = [&](char* S, int kn) {
    gl_lds16(pA[0] + kn, S + 0     + tq);
    gl_lds16(pA[1] + kn, S + 8192  + tq);
    gl_lds16(pB1   + kn, S + 16384 + tq);
    gl_lds16(pB2   + kn, S + 24576 + tq);
  };

  char* b0 = (char*)&L[0][0];
  char* b1 = (char*)&L[1][0];
  char* b2 = (char*)&L[2][0];
  STAGE(b0, 0);
  STAGE(b1, 32);

  #pragma unroll 1
  for (int t = 0; t < 32; ++t) {
    if (t < 31) { WAIT_VM(4); } else { WAIT_VM0(); }   // tile t landed; t+1 stays in flight
    BAR();                                             // all waves' tile-t data visible
    short8 a[4], b[4];
    #pragma unroll
    for (int m = 0; m < 4; ++m) a[m] = *(const short8*)(b0 + rdA + m*1024);
    #pragma unroll
    for (int n = 0; n < 4; ++n) b[n] = *(const short8*)(b0 + 16384 + rdB + n*1024);
    if (t < 30) STAGE(b2, (t + 2) * 32);               // b2 was read at t-1; all waves past this BAR => safe
    #pragma unroll
    for (int m = 0; m < 4; ++m)
      #pragma unroll
      for (int n = 0; n < 4; ++n)
        acc1[m][n] = __builtin_amdgcn_mfma_f32_16x16x32_bf16(a[m], b[n], acc1[m][n], 0, 0, 0);
    #pragma unroll
    for (int n = 0; n < 4; ++n) b[n] = *(const short8*)(b0 + 24576 + rdB + n*1024);
    #pragma unroll
    for (int m = 0; m < 4; ++m)
      #pragma unroll
      for (int n = 0; n < 4; ++n)
        acc2[m][n] = __builtin_amdgcn_mfma_f32_16x16x32_bf16(a[m], b[n], acc2[m][n], 0, 0, 0);
    char* tmp = b0; b0 = b1; b1 = b2; b2 = tmp;
  }
  // epilogue: silu(h1)*h2 -> act
  #pragma unroll
  for (int m = 0; m < 4; ++m) {
    int trb = wm*64 + m*16 + kg*4;
    #pragma unroll
    for (int n = 0; n < 4; ++n) {
      int col = n0 + wn*64 + n*16 + r16;
      #pragma unroll
      for (int j = 0; j < 4; ++j) {
        int tr = trb + j;
        if (mbase + tr < mend) {
          float h1 = acc1[m][n][j], h2 = acc2[m][n][j];
          float sv = h1 / (1.f + __expf(-h1)) * h2;
          act[(size_t)(arow0 + tr) * HID + col] = f2bf(sv);
        }
      }
    }
  }
}

// ============ down-proj, BM=256/BN=256/BK=32, merged shared+routed ============
// Depth-2 counted-vmcnt pipeline, 3 LDS buffers (96 KB), one barrier per K-tile.
// 512 threads = 8 waves (2M x 4N). Per buf 32KB: A[256][32]@0, B[256][32]@16384.
__global__ __launch_bounds__(512, 2) void k_down(const unsigned short* __restrict__ act,
    const unsigned short* __restrict__ wt, const int* __restrict__ offs,
    float* __restrict__ out, unsigned short* __restrict__ routed)
{
  __shared__ __align__(16) unsigned short L[3][16384];   // 96 KB
  int tid = threadIdx.x, lane = tid & 63, w = tid >> 6;
  int nb = blockIdx.x, yb = blockIdx.y;
  int mbase, mend, arow0; const unsigned short* w3; bool is_sh;
  if (yb < 256) {
    int seg = yb >> 5, mb = yb & 31;
    int s0 = offs[seg], s1 = offs[seg+1];
    mbase = s0 + mb*256; if (mbase >= s1) return;
    mend = s1; arow0 = mbase;
    w3 = wt + (size_t)(16+seg) * MATE; is_sh = false;
  } else {
    int mb = yb - 256; mbase = mb*256; mend = NTOK; arow0 = 16384 + mbase;
    w3 = wt + (size_t)26 * MATE; is_sh = true;
  }
  int srow = w*16 + (lane >> 2);
  int swz = (((lane & 3) ^ ((lane >> 3) & 3))) * 8;
  const unsigned short* pA[2];
  #pragma unroll
  for (int j = 0; j < 2; ++j)
    pA[j] = act + (size_t)(arow0 + j*128 + srow) * HID + swz;
  int n0b = nb * 256;
  const unsigned short* pB[2];
  #pragma unroll
  for (int j = 0; j < 2; ++j)
    pB[j] = w3 + (size_t)(n0b + j*128 + srow) * HID + swz;
  unsigned tq = (unsigned)tid * 16u;
  int r16 = lane & 15, kg = lane >> 4, wm = w >> 2, wn = w & 3;
  int rk = (r16 >> 1) & 3;
  int rdA = (wm*128 + r16)*64 + ((kg ^ rk) << 4);
  int rdB = 16384 + (wn*64 + r16)*64 + ((kg ^ rk) << 4);
  const f32x4 fz = {0.f,0.f,0.f,0.f};
  f32x4 acc[8][4];
  #pragma unroll
  for (int m = 0; m < 8; ++m)
    #pragma unroll
    for (int n = 0; n < 4; ++n) acc[m][n] = fz;

  auto STAGE = [&](char* S, int kn) {
    gl_lds16(pA[0] + kn, S + 0     + tq);
    gl_lds16(pA[1] + kn, S + 8192  + tq);
    gl_lds16(pB[0] + kn, S + 16384 + tq);
    gl_lds16(pB[1] + kn, S + 24576 + tq);
  };

  char* b0 = (char*)&L[0][0];
  char* b1 = (char*)&L[1][0];
  char* b2 = (char*)&L[2][0];
  STAGE(b0, 0);
  STAGE(b1, 32);

  #pragma unroll 1
  for (int t = 0; t < 64; ++t) {
    if (t < 63) { WAIT_VM(4); } else { WAIT_VM0(); }
    BAR();
    short8 a[4], b[4];
    #pragma unroll
    for (int m = 0; m < 4; ++m) a[m] = *(const short8*)(b0 + rdA + m*1024);
    #pragma unroll
    for (int n = 0; n < 4; ++n) b[n] = *(const short8*)(b0 + rdB + n*1024);
    if (t < 62) STAGE(b2, (t + 2) * 32);
    #pragma unroll
    for (int m = 0; m < 4; ++m)
      #pragma unroll
      for (int n = 0; n < 4; ++n)
        acc[m][n] = __builtin_amdgcn_mfma_f32_16x16x32_bf16(a[m], b[n], acc[m][n], 0, 0, 0);
    #pragma unroll
    for (int m = 0; m < 4; ++m) a[m] = *(const short8*)(b0 + rdA + (4+m)*1024);
    #pragma unroll
    for (int m = 0; m < 4; ++m)
      #pragma unroll
      for (int n = 0; n < 4; ++n)
        acc[4+m][n] = __builtin_amdgcn_mfma_f32_16x16x32_bf16(a[m], b[n], acc[4+m][n], 0, 0, 0);
    char* tmp = b0; b0 = b1; b1 = b2; b2 = tmp;
  }
  #pragma unroll
  for (int m = 0; m < 8; ++m) {
    int trb = wm*128 + m*16 + kg*4;
    #pragma unroll
    for (int n = 0; n < 4; ++n) {
      int col = n0b + wn*64 + n*16 + r16;
      #pragma unroll
      for (int j = 0; j < 4; ++j) {
        int tr = trb + j;
        if (mbase + tr < mend) {
          float val = acc[m][n][j];
          if (is_sh) {
            out[(size_t)(mbase + tr) * DIM + col] = val;
          } else {
            routed[(size_t)(mbase + tr) * DIM + col] = f2bf(val);
          }
        }
      }
    }
  }
}

// ------------- combine: out[t] += w0*routed[slot0[t]] + w1*routed[slot1[t]] -------------
__global__ __launch_bounds__(256) void k_comb(float* __restrict__ out,
    const unsigned short* __restrict__ routed, const int* __restrict__ slot,
    const float* __restrict__ topw)
{
  int t = blockIdx.x;
  int d4 = threadIdx.x;
  int s0 = slot[2*t], s1 = slot[2*t+1];
  float w0 = topw[2*t], w1 = topw[2*t+1];
  float4 o = reinterpret_cast<float4*>(out + (size_t)t * DIM)[d4];
  ushort4 r0 = reinterpret_cast<const ushort4*>(routed + (size_t)s0 * DIM)[d4];
  ushort4 r1 = reinterpret_cast<const ushort4*>(routed + (size_t)s1 * DIM)[d4];
  o.x += w0*bf2f(r0.x) + w1*bf2f(r1.x);
  o.y += w0*bf2f(r0.y) + w1*bf2f(r1.y);
  o.z += w0*bf2f(r0.z) + w1*bf2f(r1.z);
  o.w += w0*bf2f(r0.w) + w1*bf2f(r1.w);
  reinterpret_cast<float4*>(out + (size_t)t * DIM)[d4] = o;
}

extern "C" void kernel_launch(void* const* d_in, const int* in_sizes, int n_in,
                              void* d_out, int out_size, void* d_ws, size_t ws_size,
                              hipStream_t stream)
{
  const float* x   = (const float*)d_in[0];
  const float* gw  = (const float*)d_in[1];
  const float* ew1 = (const float*)d_in[2];
  const float* ew2 = (const float*)d_in[3];
  const float* ew3 = (const float*)d_in[4];
  const float* sw1 = (const float*)d_in[5];
  const float* sw2 = (const float*)d_in[6];
  const float* sw3 = (const float*)d_in[7];
  float* out = (float*)d_out;
  char* ws = (char*)d_ws;

  int*   counts = (int*)ws;
  int*   offs   = counts + 8;
  int*   fill   = offs + 9;
  int*   topi   = fill + 8;
  float* topw   = (float*)(topi + 2*NTOK);
  int*   entry  = (int*)(topw + 2*NTOK);
  int*   slot   = entry + 2*NTOK;
  unsigned short* xb     = (unsigned short*)(ws + (1u<<20));
  unsigned short* act    = (unsigned short*)(ws + (17u<<20));
  unsigned short* wt     = (unsigned short*)(ws + (113u<<20));
  unsigned short* routed = (unsigned short*)(ws + (221u<<20));

  hipMemsetAsync(counts, 0, 8*sizeof(int), stream);
  k_gate<<<NTOK/4, 256, 0, stream>>>(x, gw, topi, topw, counts, xb);
  k_scan<<<1, 64, 0, stream>>>(counts, offs, fill);
  k_scatter<<<NTOK/256, 256, 0, stream>>>(topi, fill, entry, slot);
  k_tr<<<3456, 256, 0, stream>>>(ew1, ew2, ew3, sw1, sw2, sw3, wt);
  k_up<<<dim3(16, 288), 512, 0, stream>>>(xb, wt, offs, entry, act);
  k_down<<<dim3(4, 288), 512, 0, stream>>>(act, wt, offs, out, routed);
  k_comb<<<NTOK, 256, 0, stream>>>(out, routed, slot, topw);
}

// Round 13
// 653.552 us; speedup vs baseline: 1.0503x; 1.0503x over previous
//
#include <hip/hip_runtime.h>
#include <cstdint>

#define NTOK 8192
#define DIM  1024
#define HID  2048
#define MATE (2048*1024)

typedef __attribute__((ext_vector_type(8))) short short8;
typedef __attribute__((ext_vector_type(4))) float f32x4;

typedef unsigned int __attribute__((address_space(1)))* gptr_t;
typedef unsigned int __attribute__((address_space(3)))* lptr_t;

__device__ __forceinline__ unsigned short f2bf(float f) {
  unsigned u = __builtin_bit_cast(unsigned, f);
  u += 0x7fffu + ((u >> 16) & 1u);
  return (unsigned short)(u >> 16);
}
__device__ __forceinline__ float bf2f(unsigned short h) {
  unsigned u = ((unsigned)h) << 16;
  return __builtin_bit_cast(float, u);
}

__device__ __forceinline__ void gl_lds16(const void* g, void* l) {
  __builtin_amdgcn_global_load_lds((gptr_t)g, (lptr_t)l, 16, 0, 0);
}

#define BAR()        asm volatile("s_barrier" ::: "memory")
#define WAIT_VM0()   asm volatile("s_waitcnt vmcnt(0)" ::: "memory")

// ---------------- fused: weight transpose (blocks 0..3455) + gating/cast (3456..5503) ----------------
__global__ __launch_bounds__(256) void k_pre(const float* __restrict__ ew1,
    const float* __restrict__ ew2, const float* __restrict__ ew3,
    const float* __restrict__ sw1, const float* __restrict__ sw2,
    const float* __restrict__ sw3, unsigned short* __restrict__ wt,
    const float* __restrict__ x, const float* __restrict__ gw,
    int* __restrict__ topi, float* __restrict__ topw, int* __restrict__ counts,
    unsigned short* __restrict__ xb)
{
  __shared__ float tile[128][129];
  if (blockIdx.x >= 3456) {
    // ---- gate + x->bf16 ----
    int g = blockIdx.x - 3456;
    int lane = threadIdx.x & 63;
    int t = g * 4 + (threadIdx.x >> 6);
    const float* xr = x + (size_t)t * DIM;
    unsigned short* xbr = xb + (size_t)t * DIM;
    float a0=0,a1=0,a2=0,a3=0,a4=0,a5=0,a6=0,a7=0;
    for (int i = 0; i < 16; ++i) {
      int idx = lane + (i << 6);
      float xv = xr[idx];
      xbr[idx] = f2bf(xv);
      float4 g0 = *reinterpret_cast<const float4*>(gw + idx*8);
      float4 g1 = *reinterpret_cast<const float4*>(gw + idx*8 + 4);
      a0 += xv*g0.x; a1 += xv*g0.y; a2 += xv*g0.z; a3 += xv*g0.w;
      a4 += xv*g1.x; a5 += xv*g1.y; a6 += xv*g1.z; a7 += xv*g1.w;
    }
    float acc[8] = {a0,a1,a2,a3,a4,a5,a6,a7};
    #pragma unroll
    for (int e = 0; e < 8; ++e)
      for (int off = 32; off >= 1; off >>= 1)
        acc[e] += __shfl_xor(acc[e], off, 64);
    if (lane == 0) {
      int i0 = 0; float v0 = acc[0];
      #pragma unroll
      for (int e = 1; e < 8; ++e) if (acc[e] > v0) { v0 = acc[e]; i0 = e; }
      int i1 = -1; float v1 = -3.4e38f;
      #pragma unroll
      for (int e = 0; e < 8; ++e) if (e != i0 && acc[e] > v1) { v1 = acc[e]; i1 = e; }
      float p0 = 1.f / (1.f + __expf(v1 - v0));
      topi[2*t] = i0; topi[2*t+1] = i1;
      topw[2*t] = p0; topw[2*t+1] = 1.f - p0;
      atomicAdd(&counts[i0], 1); atomicAdd(&counts[i1], 1);
    }
    return;
  }
  // ---- transpose+cast: src f32 [R][C] -> dst bf16 [C][R], 128x128 tiles ----
  int id = blockIdx.x;
  int z = id >> 7, t = id & 127;
  const float* src; int R, C;
  if (z < 8)        { src = ew1 + (size_t)z * MATE;      R = 1024; C = 2048; }
  else if (z < 16)  { src = ew2 + (size_t)(z-8) * MATE;  R = 1024; C = 2048; }
  else if (z < 24)  { src = ew3 + (size_t)(z-16) * MATE; R = 2048; C = 1024; }
  else if (z == 24) { src = sw1; R = 1024; C = 2048; }
  else if (z == 25) { src = sw2; R = 1024; C = 2048; }
  else              { src = sw3; R = 2048; C = 1024; }
  unsigned short* dst = wt + (size_t)z * MATE;
  int tr, tc;
  if (C == 2048) { tr = t >> 4; tc = t & 15; }   // 8 x 16 tiles of 128x128
  else           { tr = t >> 3; tc = t & 7;  }   // 16 x 8 tiles
  int rb = tr * 128, cb = tc * 128;
  int tid = threadIdx.x;
  {
    int r0 = tid >> 5, c4 = (tid & 31) * 4;
    #pragma unroll
    for (int i = 0; i < 16; ++i) {
      int r = r0 + i*8;
      float4 v = *reinterpret_cast<const float4*>(src + (size_t)(rb + r) * C + cb + c4);
      tile[r][c4 + 0] = v.x; tile[r][c4 + 1] = v.y;
      tile[r][c4 + 2] = v.z; tile[r][c4 + 3] = v.w;
    }
  }
  __syncthreads();
  {
    int r0 = (tid & 15) * 8, ccb = tid >> 4;   // 16 threads cover one dst row's 256B
    #pragma unroll
    for (int p = 0; p < 8; ++p) {
      int cc = ccb + p*16;
      short8 o;
      #pragma unroll
      for (int i = 0; i < 8; ++i) o[i] = (short)f2bf(tile[r0 + i][cc]);
      *reinterpret_cast<short8*>(dst + (size_t)(cb + cc) * R + rb + r0) = o;
    }
  }
}

__global__ void k_scan(const int* __restrict__ counts, int* __restrict__ offs,
                       int* __restrict__ fill)
{
  if (threadIdx.x == 0) {
    int s = 0;
    for (int e = 0; e < 8; ++e) { offs[e] = s; fill[e] = s; s += counts[e]; }
    offs[8] = s;
  }
}

__global__ __launch_bounds__(256) void k_scatter(const int* __restrict__ topi,
    int* __restrict__ fill, int* __restrict__ entry, int* __restrict__ slot)
{
  int t = blockIdx.x * 256 + threadIdx.x;
  #pragma unroll
  for (int k = 0; k < 2; ++k) {
    int e = topi[2*t + k];
    int pos = atomicAdd(&fill[e], 1);
    entry[pos] = t;
    slot[2*t + k] = pos;
  }
}

// ============ up-proj (dual-B) + SwiGLU, BM=256/BN=128x2/BK=64, 1-barrier 2-phase ============
// (R11-proven config: 235us, MfmaUtil 40%.) 512 threads = 8 waves (4M x 2N).
// LDS/buf 64KB: A[256][64]@0, B1[128][64]@32768, B2@49152.
__global__ __launch_bounds__(512, 2) void k_up(const unsigned short* __restrict__ xb,
    const unsigned short* __restrict__ wt, const int* __restrict__ offs,
    const int* __restrict__ entry, unsigned short* __restrict__ act)
{
  __shared__ __align__(16) unsigned short L[2][32768];   // 128 KB
  int tid = threadIdx.x, lane = tid & 63, w = tid >> 6;
  int nb = blockIdx.x, yb = blockIdx.y;
  int mbase, mend, arow0; const unsigned short *w1, *w2; bool is_sh;
  if (yb < 256) {
    int seg = yb >> 5, mb = yb & 31;
    int s0 = offs[seg], s1 = offs[seg+1];
    mbase = s0 + mb*256; if (mbase >= s1) return;
    mend = s1; arow0 = mbase;
    w1 = wt + (size_t)seg * MATE; w2 = wt + (size_t)(8+seg) * MATE; is_sh = false;
  } else {
    int mb = yb - 256; mbase = mb*256; mend = NTOK; arow0 = 16384 + mbase;
    w1 = wt + (size_t)24 * MATE; w2 = wt + (size_t)25 * MATE; is_sh = true;
  }
  int l8 = lane >> 3;
  int swz8 = ((lane & 7) ^ l8) * 8;
  const unsigned short* pA[4];
  #pragma unroll
  for (int j = 0; j < 4; ++j) {
    int mi = mbase + j*64 + w*8 + l8;
    int tok = is_sh ? mi : ((mi < mend) ? entry[mi] : 0);
    pA[j] = xb + (size_t)tok * DIM + swz8;
  }
  int n0 = nb * 128;
  const unsigned short *pB1[2], *pB2[2];
  #pragma unroll
  for (int j = 0; j < 2; ++j) {
    int r = n0 + j*64 + w*8 + l8;
    pB1[j] = w1 + (size_t)r * DIM + swz8;
    pB2[j] = w2 + (size_t)r * DIM + swz8;
  }
  unsigned wq = (unsigned)__builtin_amdgcn_readfirstlane(w * 1024u);
  int r16 = lane & 15, kg = lane >> 4, wm = w >> 1, wn = w & 1;
  int xr = r16 & 7;
  int rdA = (wm*64 + r16)*128 + ((kg ^ xr) << 4);
  int rdB = (wn*64 + r16)*128 + ((kg ^ xr) << 4);
  const f32x4 fz = {0.f,0.f,0.f,0.f};
  f32x4 acc1[4][4], acc2[4][4];
  #pragma unroll
  for (int m = 0; m < 4; ++m)
    #pragma unroll
    for (int n = 0; n < 4; ++n) { acc1[m][n] = fz; acc2[m][n] = fz; }

  auto STAGE = [&](char* S, int kn) {
    gl_lds16(pA[0]  + kn, S + 0     + wq);
    gl_lds16(pA[1]  + kn, S + 8192  + wq);
    gl_lds16(pA[2]  + kn, S + 16384 + wq);
    gl_lds16(pA[3]  + kn, S + 24576 + wq);
    gl_lds16(pB1[0] + kn, S + 32768 + wq);
    gl_lds16(pB1[1] + kn, S + 40960 + wq);
    gl_lds16(pB2[0] + kn, S + 49152 + wq);
    gl_lds16(pB2[1] + kn, S + 57344 + wq);
  };

  STAGE((char*)&L[0][0], 0);
  WAIT_VM0(); BAR();
  const char* Bp = (const char*)&L[0][0];
  char* Sp = (char*)&L[1][0];

  #pragma unroll 1
  for (int t = 0; t < 16; ++t) {
    short8 a[4], b[4];
    #pragma unroll
    for (int m = 0; m < 4; ++m) a[m] = *(const short8*)(Bp + rdA + m*2048);
    #pragma unroll
    for (int n = 0; n < 4; ++n) b[n] = *(const short8*)(Bp + 32768 + rdB + n*2048);
    if (t < 15) STAGE(Sp, (t + 1) * 64);
    #pragma unroll
    for (int m = 0; m < 4; ++m)
      #pragma unroll
      for (int n = 0; n < 4; ++n)
        acc1[m][n] = __builtin_amdgcn_mfma_f32_16x16x32_bf16(a[m], b[n], acc1[m][n], 0, 0, 0);
    #pragma unroll
    for (int n = 0; n < 4; ++n) b[n] = *(const short8*)(Bp + 49152 + rdB + n*2048);
    #pragma unroll
    for (int m = 0; m < 4; ++m)
      #pragma unroll
      for (int n = 0; n < 4; ++n)
        acc2[m][n] = __builtin_amdgcn_mfma_f32_16x16x32_bf16(a[m], b[n], acc2[m][n], 0, 0, 0);
    #pragma unroll
    for (int m = 0; m < 4; ++m) a[m] = *(const short8*)(Bp + (rdA^64) + m*2048);
    #pragma unroll
    for (int n = 0; n < 4; ++n) b[n] = *(const short8*)(Bp + 32768 + (rdB^64) + n*2048);
    #pragma unroll
    for (int m = 0; m < 4; ++m)
      #pragma unroll
      for (int n = 0; n < 4; ++n)
        acc1[m][n] = __builtin_amdgcn_mfma_f32_16x16x32_bf16(a[m], b[n], acc1[m][n], 0, 0, 0);
    #pragma unroll
    for (int n = 0; n < 4; ++n) b[n] = *(const short8*)(Bp + 49152 + (rdB^64) + n*2048);
    #pragma unroll
    for (int m = 0; m < 4; ++m)
      #pragma unroll
      for (int n = 0; n < 4; ++n)
        acc2[m][n] = __builtin_amdgcn_mfma_f32_16x16x32_bf16(a[m], b[n], acc2[m][n], 0, 0, 0);
    WAIT_VM0();
    BAR();
    char* tmp = (char*)Bp; Bp = Sp; Sp = tmp;
  }
  #pragma unroll
  for (int m = 0; m < 4; ++m) {
    int trb = wm*64 + m*16 + kg*4;
    #pragma unroll
    for (int n = 0; n < 4; ++n) {
      int col = n0 + wn*64 + n*16 + r16;
      #pragma unroll
      for (int j = 0; j < 4; ++j) {
        int tr = trb + j;
        if (mbase + tr < mend) {
          float h1 = acc1[m][n][j], h2 = acc2[m][n][j];
          float sv = h1 / (1.f + __expf(-h1)) * h2;
          act[(size_t)(arow0 + tr) * HID + col] = f2bf(sv);
        }
      }
    }
  }
}

// ============ down-proj, BM=256/BN=256/BK=64, merged shared+routed, 1-barrier 2-phase ============
// (R11-proven config.) 512 threads = 8 waves (2M x 4N), wave tile 128x64.
__global__ __launch_bounds__(512, 2) void k_down(const unsigned short* __restrict__ act,
    const unsigned short* __restrict__ wt, const int* __restrict__ offs,
    float* __restrict__ out, unsigned short* __restrict__ routed)
{
  __shared__ __align__(16) unsigned short L[2][32768];   // 128 KB
  int tid = threadIdx.x, lane = tid & 63, w = tid >> 6;
  int nb = blockIdx.x, yb = blockIdx.y;
  int mbase, mend, arow0; const unsigned short* w3; bool is_sh;
  if (yb < 256) {
    int seg = yb >> 5, mb = yb & 31;
    int s0 = offs[seg], s1 = offs[seg+1];
    mbase = s0 + mb*256; if (mbase >= s1) return;
    mend = s1; arow0 = mbase;
    w3 = wt + (size_t)(16+seg) * MATE; is_sh = false;
  } else {
    int mb = yb - 256; mbase = mb*256; mend = NTOK; arow0 = 16384 + mbase;
    w3 = wt + (size_t)26 * MATE; is_sh = true;
  }
  int l8 = lane >> 3;
  int swz8 = ((lane & 7) ^ l8) * 8;
  const unsigned short* pA[4];
  #pragma unroll
  for (int j = 0; j < 4; ++j)
    pA[j] = act + (size_t)(arow0 + j*64 + w*8 + l8) * HID + swz8;
  int n0b = nb * 256;
  const unsigned short* pB[4];
  #pragma unroll
  for (int j = 0; j < 4; ++j)
    pB[j] = w3 + (size_t)(n0b + j*64 + w*8 + l8) * HID + swz8;
  unsigned wq = (unsigned)__builtin_amdgcn_readfirstlane(w * 1024u);
  int r16 = lane & 15, kg = lane >> 4, wm = w >> 2, wn = w & 3;
  int xr = r16 & 7;
  int rdA = (wm*128 + r16)*128 + ((kg ^ xr) << 4);
  int rdB = (wn*64 + r16)*128 + ((kg ^ xr) << 4);
  const f32x4 fz = {0.f,0.f,0.f,0.f};
  f32x4 acc[8][4];
  #pragma unroll
  for (int m = 0; m < 8; ++m)
    #pragma unroll
    for (int n = 0; n < 4; ++n) acc[m][n] = fz;

  auto STAGE = [&](char* S, int kn) {
    gl_lds16(pA[0] + kn, S + 0     + wq);
    gl_lds16(pA[1] + kn, S + 8192  + wq);
    gl_lds16(pA[2] + kn, S + 16384 + wq);
    gl_lds16(pA[3] + kn, S + 24576 + wq);
    gl_lds16(pB[0] + kn, S + 32768 + wq);
    gl_lds16(pB[1] + kn, S + 40960 + wq);
    gl_lds16(pB[2] + kn, S + 49152 + wq);
    gl_lds16(pB[3] + kn, S + 57344 + wq);
  };

  STAGE((char*)&L[0][0], 0);
  WAIT_VM0(); BAR();
  const char* Bp = (const char*)&L[0][0];
  char* Sp = (char*)&L[1][0];

  #pragma unroll 1
  for (int t = 0; t < 32; ++t) {
    short8 a[4], b[4];
    #pragma unroll
    for (int m = 0; m < 4; ++m) a[m] = *(const short8*)(Bp + rdA + m*2048);
    #pragma unroll
    for (int n = 0; n < 4; ++n) b[n] = *(const short8*)(Bp + 32768 + rdB + n*2048);
    if (t < 31) STAGE(Sp, (t + 1) * 64);
    #pragma unroll
    for (int m = 0; m < 4; ++m)
      #pragma unroll
      for (int n = 0; n < 4; ++n)
        acc[m][n] = __builtin_amdgcn_mfma_f32_16x16x32_bf16(a[m], b[n], acc[m][n], 0, 0, 0);
    #pragma unroll
    for (int m = 0; m < 4; ++m) a[m] = *(const short8*)(Bp + rdA + (4+m)*2048);
    #pragma unroll
    for (int m = 0; m < 4; ++m)
      #pragma unroll
      for (int n = 0; n < 4; ++n)
        acc[4+m][n] = __builtin_amdgcn_mfma_f32_16x16x32_bf16(a[m], b[n], acc[4+m][n], 0, 0, 0);
    #pragma unroll
    for (int m = 0; m < 4; ++m) a[m] = *(const short8*)(Bp + (rdA^64) + m*2048);
    #pragma unroll
    for (int n = 0; n < 4; ++n) b[n] = *(const short8*)(Bp + 32768 + (rdB^64) + n*2048);
    #pragma unroll
    for (int m = 0; m < 4; ++m)
      #pragma unroll
      for (int n = 0; n < 4; ++n)
        acc[m][n] = __builtin_amdgcn_mfma_f32_16x16x32_bf16(a[m], b[n], acc[m][n], 0, 0, 0);
    #pragma unroll
    for (int m = 0; m < 4; ++m) a[m] = *(const short8*)(Bp + (rdA^64) + (4+m)*2048);
    #pragma unroll
    for (int m = 0; m < 4; ++m)
      #pragma unroll
      for (int n = 0; n < 4; ++n)
        acc[4+m][n] = __builtin_amdgcn_mfma_f32_16x16x32_bf16(a[m], b[n], acc[4+m][n], 0, 0, 0);
    WAIT_VM0();
    BAR();
    char* tmp = (char*)Bp; Bp = Sp; Sp = tmp;
  }
  #pragma unroll
  for (int m = 0; m < 8; ++m) {
    int trb = wm*128 + m*16 + kg*4;
    #pragma unroll
    for (int n = 0; n < 4; ++n) {
      int col = n0b + wn*64 + n*16 + r16;
      #pragma unroll
      for (int j = 0; j < 4; ++j) {
        int tr = trb + j;
        if (mbase + tr < mend) {
          float val = acc[m][n][j];
          if (is_sh) {
            out[(size_t)(mbase + tr) * DIM + col] = val;
          } else {
            routed[(size_t)(mbase + tr) * DIM + col] = f2bf(val);
          }
        }
      }
    }
  }
}

// ------------- combine: out[t] += w0*routed[slot0[t]] + w1*routed[slot1[t]] -------------
__global__ __launch_bounds__(256) void k_comb(float* __restrict__ out,
    const unsigned short* __restrict__ routed, const int* __restrict__ slot,
    const float* __restrict__ topw)
{
  int t = blockIdx.x;
  int d4 = threadIdx.x;
  int s0 = slot[2*t], s1 = slot[2*t+1];
  float w0 = topw[2*t], w1 = topw[2*t+1];
  float4 o = reinterpret_cast<float4*>(out + (size_t)t * DIM)[d4];
  ushort4 r0 = reinterpret_cast<const ushort4*>(routed + (size_t)s0 * DIM)[d4];
  ushort4 r1 = reinterpret_cast<const ushort4*>(routed + (size_t)s1 * DIM)[d4];
  o.x += w0*bf2f(r0.x) + w1*bf2f(r1.x);
  o.y += w0*bf2f(r0.y) + w1*bf2f(r1.y);
  o.z += w0*bf2f(r0.z) + w1*bf2f(r1.z);
  o.w += w0*bf2f(r0.w) + w1*bf2f(r1.w);
  reinterpret_cast<float4*>(out + (size_t)t * DIM)[d4] = o;
}

extern "C" void kernel_launch(void* const* d_in, const int* in_sizes, int n_in,
                              void* d_out, int out_size, void* d_ws, size_t ws_size,
                              hipStream_t stream)
{
  const float* x   = (const float*)d_in[0];
  const float* gw  = (const float*)d_in[1];
  const float* ew1 = (const float*)d_in[2];
  const float* ew2 = (const float*)d_in[3];
  const float* ew3 = (const float*)d_in[4];
  const float* sw1 = (const float*)d_in[5];
  const float* sw2 = (const float*)d_in[6];
  const float* sw3 = (const float*)d_in[7];
  float* out = (float*)d_out;
  char* ws = (char*)d_ws;

  int*   counts = (int*)ws;
  int*   offs   = counts + 8;
  int*   fill   = offs + 9;
  int*   topi   = fill + 8;
  float* topw   = (float*)(topi + 2*NTOK);
  int*   entry  = (int*)(topw + 2*NTOK);
  int*   slot   = entry + 2*NTOK;
  unsigned short* xb     = (unsigned short*)(ws + (1u<<20));
  unsigned short* act    = (unsigned short*)(ws + (17u<<20));
  unsigned short* wt     = (unsigned short*)(ws + (113u<<20));
  unsigned short* routed = (unsigned short*)(ws + (221u<<20));

  hipMemsetAsync(counts, 0, 8*sizeof(int), stream);
  k_pre<<<5504, 256, 0, stream>>>(ew1, ew2, ew3, sw1, sw2, sw3, wt,
                                  x, gw, topi, topw, counts, xb);
  k_scan<<<1, 64, 0, stream>>>(counts, offs, fill);
  k_scatter<<<NTOK/256, 256, 0, stream>>>(topi, fill, entry, slot);
  k_up<<<dim3(16, 288), 512, 0, stream>>>(xb, wt, offs, entry, act);
  k_down<<<dim3(4, 288), 512, 0, stream>>>(act, wt, offs, out, routed);
  k_comb<<<NTOK, 256, 0, stream>>>(out, routed, slot, topw);
}